// Round 1
// baseline (149.926 us; speedup 1.0000x reference)
//
#include <hip/hip_runtime.h>
#include <stdint.h>

// BinaryTreeLogicNet: out = sigmoid(tree_gcd(sigmoid(x @ W^T - 2)) * w_out + b_out)
// M=65536 rows, L=256 leaves. Fused single kernel:
//   - bf16 MFMA 16x16x32 GEMM, A direct from global (wave-private rows),
//     W staged fp32->bf16 into LDS per 64-wide K tile (padded stride 72,
//     rows nibble-swap permuted so each lane holds a contiguous 16-leaf subtree)
//   - tree levels 1-4 register-local, levels 5-8 via shfl_xor butterfly
// Block = 256 thr (4 waves), 64 rows/block -> 1024 blocks. Memory-bound (~64MB x).

#define EPS 1e-6f
#define LOG2E 1.44269504088896340736f
#define STR 72   // LDS row stride in bf16 elems (64 + 8 pad; 144B keeps 16B align, breaks bank conflict)

typedef __attribute__((ext_vector_type(8))) short short8;     // bf16x8 MFMA frag (4 VGPR)
typedef __attribute__((ext_vector_type(4))) short short4_t;   // 8B LDS store
typedef __attribute__((ext_vector_type(4))) float float4_t;   // MFMA acc

__device__ __forceinline__ float fast_sigmoid(float z) {
    float e = __builtin_amdgcn_exp2f(-z * LOG2E);
    return __builtin_amdgcn_rcpf(1.0f + e);
}

__device__ __forceinline__ short f2bf(float f) {   // fp32 -> bf16 RNE
    uint32_t u = __builtin_bit_cast(uint32_t, f);
    u += 0x7FFFu + ((u >> 16) & 1u);
    return (short)(u >> 16);
}

__device__ __forceinline__ float ggcd(float l, float r, float lam) {
    float a = fabsf(l) + EPS;
    float b = fabsf(r) + EPS;
    float mn = fminf(a, b);
    float mx = fmaxf(a, b);
    return fmaf(lam, mn - mx, mx);   // lam*mn + (1-lam)*mx
}

__global__ __launch_bounds__(256, 3)
void btln_kernel(const float* __restrict__ x, const float* __restrict__ Wl,
                 const float* __restrict__ wts, const float* __restrict__ bia,
                 const float* __restrict__ wout, const float* __restrict__ bout,
                 float* __restrict__ out) {
    __shared__ short Ws[256 * STR];          // 36864 B
    __shared__ float w0v[256], w1v[256], lamv[256];

    const int tid  = threadIdx.x;
    const int lane = tid & 63;
    const int wv   = tid >> 6;               // wave 0..3
    const int c0   = lane & 15;              // MFMA col-in-tile / n-index
    const int q    = lane >> 4;              // MFMA quad

    // node params once per block (255 tree nodes)
    if (tid < 255) {
        w0v[tid]  = wts[2 * tid];
        w1v[tid]  = wts[2 * tid + 1];
        lamv[tid] = fast_sigmoid(bia[tid]);
    }

    const int rowbase = blockIdx.x * 64 + wv * 16;     // this wave's 16 rows
    const float* xrow = x + (size_t)(rowbase + c0) * 256;

    float4_t acc[16];
    #pragma unroll
    for (int t = 0; t < 16; ++t) acc[t] = (float4_t){0.f, 0.f, 0.f, 0.f};

    const float4* Wv4 = (const float4*)Wl;

    for (int kt = 0; kt < 4; ++kt) {
        const int k0 = kt * 64;
        if (kt) __syncthreads();             // consumers done before overwrite
        // stage W tile: 256 rows x 64 cols, fp32->bf16, permuted rows
        #pragma unroll
        for (int it = 0; it < 16; ++it) {
            int f  = it * 256 + tid;          // float4 index within tile
            int j  = f >> 4;                  // source row (logical column)
            int kc = f & 15;                  // float4 within row
            float4 w4 = Wv4[j * 64 + (k0 >> 2) + kc];
            int p = ((j & 15) << 4) | (j >> 4);   // nibble-swap: lane-subtree layout
            short4_t s4;
            s4.x = f2bf(w4.x); s4.y = f2bf(w4.y);
            s4.z = f2bf(w4.z); s4.w = f2bf(w4.w);
            *(short4_t*)&Ws[p * STR + kc * 4] = s4;
        }
        __syncthreads();

        #pragma unroll
        for (int kk = 0; kk < 64; kk += 32) {
            // A fragment: A[m=lane&15][k=q*8+j], 8 consecutive floats
            const float4* ap = (const float4*)(xrow + k0 + kk + q * 8);
            float4 a0 = ap[0], a1 = ap[1];
            short8 af;
            af[0] = f2bf(a0.x); af[1] = f2bf(a0.y); af[2] = f2bf(a0.z); af[3] = f2bf(a0.w);
            af[4] = f2bf(a1.x); af[5] = f2bf(a1.y); af[6] = f2bf(a1.z); af[7] = f2bf(a1.w);
            #pragma unroll
            for (int t = 0; t < 16; ++t) {
                short8 bf = *(const short8*)&Ws[(t * 16 + c0) * STR + kk + q * 8];
                acc[t] = __builtin_amdgcn_mfma_f32_16x16x32_bf16(af, bf, acc[t], 0, 0, 0);
            }
        }
    }

    // ---- epilogue: leaf sigmoid + tree reduction ----
    // acc[t][r]: row = q*4+r, physical col = 16t+c0, logical leaf = c0*16+t
    const float wo = wout[0];
    const float bo = bout[0];

    float res[4];
    #pragma unroll
    for (int r = 0; r < 4; ++r) {
        float s[16];
        #pragma unroll
        for (int t = 0; t < 16; ++t) s[t] = fast_sigmoid(acc[t][r] - 2.0f);
        // level 1 (off 0, m=128): node = c0*8+tp
        #pragma unroll
        for (int tp = 0; tp < 8; ++tp) {
            int n = c0 * 8 + tp;
            s[tp] = ggcd(s[2*tp] * w0v[n], s[2*tp+1] * w1v[n], lamv[n]);
        }
        // level 2 (off 128)
        #pragma unroll
        for (int tp = 0; tp < 4; ++tp) {
            int n = 128 + c0 * 4 + tp;
            s[tp] = ggcd(s[2*tp] * w0v[n], s[2*tp+1] * w1v[n], lamv[n]);
        }
        // level 3 (off 192)
        #pragma unroll
        for (int tp = 0; tp < 2; ++tp) {
            int n = 192 + c0 * 2 + tp;
            s[tp] = ggcd(s[2*tp] * w0v[n], s[2*tp+1] * w1v[n], lamv[n]);
        }
        // level 4 (off 224)
        {
            int n = 224 + c0;
            res[r] = ggcd(s[0] * w0v[n], s[1] * w1v[n], lamv[n]);
        }
    }

    // levels 5-8: butterfly across c0 (bits 0..3); all lanes converge
    const int offs[4] = {240, 248, 252, 254};
    #pragma unroll
    for (int k = 0; k < 4; ++k) {
        int n = offs[k] + (c0 >> (k + 1));
        float w0n = w0v[n], w1n = w1v[n], lm = lamv[n];
        bool isLeft = ((c0 >> k) & 1) == 0;
        #pragma unroll
        for (int r = 0; r < 4; ++r) {
            float other = __shfl_xor(res[r], 1 << k, 64);
            float lf = isLeft ? res[r] : other;
            float rt = isLeft ? other  : res[r];
            res[r] = ggcd(lf * w0n, rt * w1n, lm);
        }
    }

    if (c0 == 0) {
        #pragma unroll
        for (int r = 0; r < 4; ++r) {
            out[rowbase + q * 4 + r] = fast_sigmoid(fmaf(res[r], wo, bo));
        }
    }
}

extern "C" void kernel_launch(void* const* d_in, const int* in_sizes, int n_in,
                              void* d_out, int out_size, void* d_ws, size_t ws_size,
                              hipStream_t stream) {
    const float* x   = (const float*)d_in[0];
    const float* Wl  = (const float*)d_in[1];
    const float* wts = (const float*)d_in[2];
    const float* bia = (const float*)d_in[3];
    const float* wo  = (const float*)d_in[4];
    const float* bo  = (const float*)d_in[5];
    float* out = (float*)d_out;

    const int rows = out_size;               // 65536
    dim3 grid(rows / 64), block(256);
    btln_kernel<<<grid, block, 0, stream>>>(x, Wl, wts, bia, wo, bo, out);
}

// Round 2
// 116.030 us; speedup vs baseline: 1.2921x; 1.2921x over previous
//
#include <hip/hip_runtime.h>
#include <stdint.h>

// BinaryTreeLogicNet: out = sigmoid(tree_gcd(sigmoid(x @ W^T - 2)) * w_out + b_out)
// M=65536 rows, L=256 leaves.
// R1 design: persistent-W, barrier-free main loop.
//   Pre-kernel: W fp32 -> bf16, nibble-swap row permute, stride-264 padded LDS
//   image staged into d_ws (132 KB).
//   Main kernel: 256 blocks x 1024 thr (16 waves, 1 block/CU, 135 KB LDS).
//   One cooperative copy + ONE barrier; then each wave independently does a
//   16-row group: K=256 MFMA sweep (128 mfma), tree epilogue in reg/shfl.
// Stride 264 shorts = 528 B: 16B-aligned rows; 132 dwords % 32 = 4 -> even
// 8-dword/bank distribution for the (c0,q) b128 read pattern (no excess conflicts).

#define EPS 1e-6f
#define LOG2E 1.44269504088896340736f
#define WSTR 264   // shorts per W row in LDS image (256 + 8 pad)

typedef __attribute__((ext_vector_type(8))) short short8;     // bf16x8 MFMA frag
typedef __attribute__((ext_vector_type(4))) short short4_t;   // 8B store
typedef __attribute__((ext_vector_type(4))) float float4_t;   // MFMA acc

__device__ __forceinline__ float fast_sigmoid(float z) {
    float e = __builtin_amdgcn_exp2f(-z * LOG2E);
    return __builtin_amdgcn_rcpf(1.0f + e);
}

__device__ __forceinline__ short f2bf(float f) {   // fp32 -> bf16 RNE
    uint32_t u = __builtin_bit_cast(uint32_t, f);
    u += 0x7FFFu + ((u >> 16) & 1u);
    return (short)(u >> 16);
}

__device__ __forceinline__ float ggcd(float l, float r, float lam) {
    float a = fabsf(l) + EPS;
    float b = fabsf(r) + EPS;
    float mn = fminf(a, b);
    float mx = fmaxf(a, b);
    return fmaf(lam, mn - mx, mx);   // lam*mn + (1-lam)*mx
}

// ---- pre-kernel: build bf16 LDS image of W in d_ws ----
// img[p(j)*WSTR + k] = bf16(W[j][k]),  p(j) = nibble-swap(j)
__global__ __launch_bounds__(256)
void convert_w_kernel(const float* __restrict__ Wl, short* __restrict__ img) {
    int t = blockIdx.x * 256 + threadIdx.x;   // 16384 threads, 4 elems each
    int j   = t >> 6;          // source row 0..255
    int kc4 = t & 63;          // float4 index within row
    const float4* Wv4 = (const float4*)Wl;
    float4 w4 = Wv4[j * 64 + kc4];
    int p = ((j & 15) << 4) | (j >> 4);
    short4_t s4;
    s4.x = f2bf(w4.x); s4.y = f2bf(w4.y); s4.z = f2bf(w4.z); s4.w = f2bf(w4.w);
    *(short4_t*)&img[p * WSTR + kc4 * 4] = s4;
}

// ---- main kernel ----
__global__ __launch_bounds__(1024, 4)
void btln_main(const float* __restrict__ x, const short* __restrict__ img,
               const float* __restrict__ wts, const float* __restrict__ bia,
               const float* __restrict__ wout, const float* __restrict__ bout,
               float* __restrict__ out) {
    __shared__ short Ws[256 * WSTR];            // 135168 B
    __shared__ float w0v[256], w1v[256], lamv[256];

    const int tid  = threadIdx.x;
    const int lane = tid & 63;
    const int wv   = tid >> 6;                  // wave 0..15
    const int c0   = lane & 15;
    const int q    = lane >> 4;

    // cooperative copy of the prebuilt 132 KB W image (16B chunks)
    {
        const uint4* img4 = (const uint4*)img;
        uint4* ws4 = (uint4*)Ws;
        #pragma unroll
        for (int it = 0; it < 9; ++it) {
            int i = it * 1024 + tid;
            if (i < (256 * WSTR * 2) / 16) ws4[i] = img4[i];
        }
    }
    if (tid < 255) {
        w0v[tid]  = wts[2 * tid];
        w1v[tid]  = wts[2 * tid + 1];
        lamv[tid] = fast_sigmoid(bia[tid]);
    }
    __syncthreads();                             // the ONLY barrier

    // each wave owns one 16-row group
    const int group   = blockIdx.x * 16 + wv;    // 0..4095
    const int rowbase = group * 16;
    const float* xrow = x + (size_t)(rowbase + c0) * 256;

    float4_t acc[16];
    #pragma unroll
    for (int t = 0; t < 16; ++t) acc[t] = (float4_t){0.f, 0.f, 0.f, 0.f};

    #pragma unroll
    for (int kk = 0; kk < 256; kk += 32) {
        const float4* ap = (const float4*)(xrow + kk + q * 8);
        float4 a0 = ap[0], a1 = ap[1];
        short8 af;
        af[0] = f2bf(a0.x); af[1] = f2bf(a0.y); af[2] = f2bf(a0.z); af[3] = f2bf(a0.w);
        af[4] = f2bf(a1.x); af[5] = f2bf(a1.y); af[6] = f2bf(a1.z); af[7] = f2bf(a1.w);
        #pragma unroll
        for (int t = 0; t < 16; ++t) {
            short8 bf = *(const short8*)&Ws[(t * 16 + c0) * WSTR + kk + q * 8];
            acc[t] = __builtin_amdgcn_mfma_f32_16x16x32_bf16(af, bf, acc[t], 0, 0, 0);
        }
    }

    // ---- epilogue: leaf sigmoid + tree ----
    // acc[t][r]: row = q*4+r, logical leaf = c0*16+t  (nibble-swap permute)
    const float wo = wout[0];
    const float bo = bout[0];

    float res[4];
    #pragma unroll
    for (int r = 0; r < 4; ++r) {
        float s[16];
        #pragma unroll
        for (int t = 0; t < 16; ++t) s[t] = fast_sigmoid(acc[t][r] - 2.0f);
        #pragma unroll
        for (int tp = 0; tp < 8; ++tp) {       // level 1 (off 0)
            int n = c0 * 8 + tp;
            s[tp] = ggcd(s[2*tp] * w0v[n], s[2*tp+1] * w1v[n], lamv[n]);
        }
        #pragma unroll
        for (int tp = 0; tp < 4; ++tp) {       // level 2 (off 128)
            int n = 128 + c0 * 4 + tp;
            s[tp] = ggcd(s[2*tp] * w0v[n], s[2*tp+1] * w1v[n], lamv[n]);
        }
        #pragma unroll
        for (int tp = 0; tp < 2; ++tp) {       // level 3 (off 192)
            int n = 192 + c0 * 2 + tp;
            s[tp] = ggcd(s[2*tp] * w0v[n], s[2*tp+1] * w1v[n], lamv[n]);
        }
        {                                       // level 4 (off 224)
            int n = 224 + c0;
            res[r] = ggcd(s[0] * w0v[n], s[1] * w1v[n], lamv[n]);
        }
    }

    // levels 5-8: butterfly across c0
    const int offs[4] = {240, 248, 252, 254};
    #pragma unroll
    for (int k = 0; k < 4; ++k) {
        int n = offs[k] + (c0 >> (k + 1));
        float w0n = w0v[n], w1n = w1v[n], lm = lamv[n];
        bool isLeft = ((c0 >> k) & 1) == 0;
        #pragma unroll
        for (int r = 0; r < 4; ++r) {
            float other = __shfl_xor(res[r], 1 << k, 64);
            float lf = isLeft ? res[r] : other;
            float rt = isLeft ? other  : res[r];
            res[r] = ggcd(lf * w0n, rt * w1n, lm);
        }
    }

    if (c0 == 0) {
        #pragma unroll
        for (int r = 0; r < 4; ++r) {
            out[rowbase + q * 4 + r] = fast_sigmoid(fmaf(res[r], wo, bo));
        }
    }
}

extern "C" void kernel_launch(void* const* d_in, const int* in_sizes, int n_in,
                              void* d_out, int out_size, void* d_ws, size_t ws_size,
                              hipStream_t stream) {
    const float* x   = (const float*)d_in[0];
    const float* Wl  = (const float*)d_in[1];
    const float* wts = (const float*)d_in[2];
    const float* bia = (const float*)d_in[3];
    const float* wo  = (const float*)d_in[4];
    const float* bo  = (const float*)d_in[5];
    float* out = (float*)d_out;
    short* img = (short*)d_ws;                  // 135168 B bf16 W image

    convert_w_kernel<<<dim3(64), dim3(256), 0, stream>>>(Wl, img);

    const int rows = out_size;                  // 65536
    dim3 grid(rows / (16 * 16)), block(1024);   // 256 blocks x 16 waves
    btln_main<<<grid, block, 0, stream>>>(x, img, wts, bia, wo, bo, out);
}

// Round 3
// 115.354 us; speedup vs baseline: 1.2997x; 1.0059x over previous
//
#include <hip/hip_runtime.h>
#include <stdint.h>

// BinaryTreeLogicNet: out = sigmoid(tree_gcd(sigmoid(x @ W^T - 2)) * w_out + b_out)
// M=65536 rows, L=256 leaves.
// R3: persistent-W LDS design (1 block/CU, 16 waves, one barrier) with
//   - manual 2-deep A prefetch, outer K-loop NOT unrolled (VGPR peak ~100,
//     away from the 128-reg spill cliff forced by 16 resident waves)
//   - in-place tree epilogue on acc[] (no second 64-reg array) with packed
//     float4(w0,w1,lam) node params read ONCE per node (not per r) -> epilogue
//     DS ops ~200 -> ~35 per wave; DS port is the binding pipe (~24.6k cyc/CU).
// Pre-kernel builds in d_ws: bf16 W image (nibble-swap rows, stride 264) +
// packed node-param table.

#define EPS 1e-6f
#define LOG2E 1.44269504088896340736f
#define WSTR 264                 // shorts per W row (256 + 8 pad)
#define WIMG_SHORTS (256 * WSTR) // 67584 shorts = 135168 B
#define PARAM_OFF_B (WIMG_SHORTS * 2)   // byte offset of param table in d_ws

typedef __attribute__((ext_vector_type(8))) short short8;
typedef __attribute__((ext_vector_type(4))) short short4_t;
typedef __attribute__((ext_vector_type(4))) float float4_t;

__device__ __forceinline__ float fast_sigmoid(float z) {
    float e = __builtin_amdgcn_exp2f(-z * LOG2E);
    return __builtin_amdgcn_rcpf(1.0f + e);
}

__device__ __forceinline__ short f2bf(float f) {   // fp32 -> bf16 RNE
    uint32_t u = __builtin_bit_cast(uint32_t, f);
    u += 0x7FFFu + ((u >> 16) & 1u);
    return (short)(u >> 16);
}

__device__ __forceinline__ float ggcd(float l, float r, float lam) {
    float a = fabsf(l) + EPS;
    float b = fabsf(r) + EPS;
    float mn = fminf(a, b);
    float mx = fmaxf(a, b);
    return fmaf(lam, mn - mx, mx);   // lam*mn + (1-lam)*mx
}

// ---- pre-kernel: bf16 W image + packed params into d_ws ----
__global__ __launch_bounds__(256)
void convert_w_kernel(const float* __restrict__ Wl,
                      const float* __restrict__ wts, const float* __restrict__ bia,
                      short* __restrict__ img) {
    int t = blockIdx.x * 256 + threadIdx.x;   // 16384 threads, 1 float4 each
    int j   = t >> 6;                         // source row 0..255
    int kc4 = t & 63;                         // float4 within row
    const float4* Wv4 = (const float4*)Wl;
    float4 w4 = Wv4[j * 64 + kc4];
    int p = ((j & 15) << 4) | (j >> 4);       // nibble-swap permute
    short4_t s4;
    s4.x = f2bf(w4.x); s4.y = f2bf(w4.y); s4.z = f2bf(w4.z); s4.w = f2bf(w4.w);
    *(short4_t*)&img[p * WSTR + kc4 * 4] = s4;

    if (blockIdx.x == 0) {
        float4* pv = (float4*)((char*)img + PARAM_OFF_B);
        if (threadIdx.x < 255) {
            int n = threadIdx.x;
            pv[n] = make_float4(wts[2 * n], wts[2 * n + 1], fast_sigmoid(bia[n]), 0.f);
        } else if (threadIdx.x == 255) {
            pv[255] = make_float4(0.f, 0.f, 0.f, 0.f);
        }
    }
}

// ---- main kernel ----
__global__ __launch_bounds__(1024, 4)
void btln_main(const float* __restrict__ x, const short* __restrict__ img,
               const float* __restrict__ wout, const float* __restrict__ bout,
               float* __restrict__ out) {
    __shared__ short Ws[WIMG_SHORTS];        // 135168 B
    __shared__ float4 pv[256];               // 4096 B packed (w0,w1,lam)

    const int tid  = threadIdx.x;
    const int lane = tid & 63;
    const int wv   = tid >> 6;               // wave 0..15
    const int c0   = lane & 15;
    const int q    = lane >> 4;

    // cooperative copy: W image (16B chunks) + param table
    {
        const uint4* img4 = (const uint4*)img;
        uint4* ws4 = (uint4*)Ws;
        const int n16 = (WIMG_SHORTS * 2) / 16;   // 8448
        #pragma unroll
        for (int it = 0; it < 9; ++it) {
            int i = it * 1024 + tid;
            if (i < n16) ws4[i] = img4[i];
        }
        if (tid < 256) {
            const float4* gpv = (const float4*)((const char*)img + PARAM_OFF_B);
            pv[tid] = gpv[tid];
        }
    }
    __syncthreads();                          // the ONLY barrier

    const int group   = blockIdx.x * 16 + wv;
    const int rowbase = group * 16;
    const float4* xv  = (const float4*)(x + (size_t)(rowbase + c0) * 256);

    float4_t acc[16];
    #pragma unroll
    for (int t = 0; t < 16; ++t) acc[t] = (float4_t){0.f, 0.f, 0.f, 0.f};

    // manual 2-deep pipeline over 8 K-steps of 32
    float4 a0 = xv[q * 2];
    float4 a1 = xv[q * 2 + 1];
    #pragma unroll 1
    for (int kt = 0; kt < 8; ++kt) {
        const int ktn = (kt < 7) ? kt + 1 : 7;
        float4 b0 = xv[ktn * 8 + q * 2];
        float4 b1 = xv[ktn * 8 + q * 2 + 1];

        short8 af;
        af[0] = f2bf(a0.x); af[1] = f2bf(a0.y); af[2] = f2bf(a0.z); af[3] = f2bf(a0.w);
        af[4] = f2bf(a1.x); af[5] = f2bf(a1.y); af[6] = f2bf(a1.z); af[7] = f2bf(a1.w);

        const int kk = kt * 32;
        #pragma unroll
        for (int t = 0; t < 16; ++t) {
            short8 bf = *(const short8*)&Ws[(t * 16 + c0) * WSTR + kk + q * 8];
            acc[t] = __builtin_amdgcn_mfma_f32_16x16x32_bf16(af, bf, acc[t], 0, 0, 0);
        }
        a0 = b0; a1 = b1;
    }

    // ---- epilogue, in place on acc ----
    // acc[t][r]: row = q*4+r, logical leaf = c0*16+t (nibble-swap permute)
    #pragma unroll
    for (int t = 0; t < 16; ++t) {
        #pragma unroll
        for (int r = 0; r < 4; ++r) acc[t][r] = fast_sigmoid(acc[t][r] - 2.0f);
    }
    #pragma unroll
    for (int tp = 0; tp < 8; ++tp) {          // level 1 (off 0)
        float4 p = pv[c0 * 8 + tp];
        #pragma unroll
        for (int r = 0; r < 4; ++r)
            acc[tp][r] = ggcd(acc[2*tp][r] * p.x, acc[2*tp+1][r] * p.y, p.z);
    }
    #pragma unroll
    for (int tp = 0; tp < 4; ++tp) {          // level 2 (off 128)
        float4 p = pv[128 + c0 * 4 + tp];
        #pragma unroll
        for (int r = 0; r < 4; ++r)
            acc[tp][r] = ggcd(acc[2*tp][r] * p.x, acc[2*tp+1][r] * p.y, p.z);
    }
    #pragma unroll
    for (int tp = 0; tp < 2; ++tp) {          // level 3 (off 192)
        float4 p = pv[192 + c0 * 2 + tp];
        #pragma unroll
        for (int r = 0; r < 4; ++r)
            acc[tp][r] = ggcd(acc[2*tp][r] * p.x, acc[2*tp+1][r] * p.y, p.z);
    }
    float res[4];
    {                                          // level 4 (off 224)
        float4 p = pv[224 + c0];
        #pragma unroll
        for (int r = 0; r < 4; ++r)
            res[r] = ggcd(acc[0][r] * p.x, acc[1][r] * p.y, p.z);
    }

    // levels 5-8: butterfly across c0
    const int offs[4] = {240, 248, 252, 254};
    #pragma unroll
    for (int k = 0; k < 4; ++k) {
        float4 p = pv[offs[k] + (c0 >> (k + 1))];
        bool isLeft = ((c0 >> k) & 1) == 0;
        #pragma unroll
        for (int r = 0; r < 4; ++r) {
            float other = __shfl_xor(res[r], 1 << k, 64);
            float lf = isLeft ? res[r] : other;
            float rt = isLeft ? other  : res[r];
            res[r] = ggcd(lf * p.x, rt * p.y, p.z);
        }
    }

    if (c0 == 0) {
        const float wo = wout[0];
        const float bo = bout[0];
        #pragma unroll
        for (int r = 0; r < 4; ++r)
            out[rowbase + q * 4 + r] = fast_sigmoid(fmaf(res[r], wo, bo));
    }
}

extern "C" void kernel_launch(void* const* d_in, const int* in_sizes, int n_in,
                              void* d_out, int out_size, void* d_ws, size_t ws_size,
                              hipStream_t stream) {
    const float* x   = (const float*)d_in[0];
    const float* Wl  = (const float*)d_in[1];
    const float* wts = (const float*)d_in[2];
    const float* bia = (const float*)d_in[3];
    const float* wo  = (const float*)d_in[4];
    const float* bo  = (const float*)d_in[5];
    float* out = (float*)d_out;
    short* img = (short*)d_ws;    // W image (135168 B) + params (4096 B)

    convert_w_kernel<<<dim3(64), dim3(256), 0, stream>>>(Wl, wts, bia, img);

    const int rows = out_size;    // 65536
    dim3 grid(rows / 256), block(1024);     // 256 blocks x 16 waves
    btln_main<<<grid, block, 0, stream>>>(x, img, wo, bo, out);
}